// Round 5
// baseline (251.096 us; speedup 1.0000x reference)
//
#include <hip/hip_runtime.h>
#include <stdint.h>

#define BH   (8 * 4096)
#define HDIM 1024
#define NIDX 65536
#define NSEG 8192
#define KD   1024
#define ND   1024

typedef __bf16 bf16x8 __attribute__((ext_vector_type(8)));
typedef float  f32x4  __attribute__((ext_vector_type(4)));

__device__ __forceinline__ unsigned short f2bf(float f) {
  unsigned int u = __float_as_uint(f);
  u += 0x7fffu + ((u >> 16) & 1u);   // RNE
  return (unsigned short)(u >> 16);
}

__device__ __forceinline__ float bf2f(unsigned short u) {
  return __uint_as_float((unsigned int)u << 16);
}

__device__ __forceinline__ void async16(const void* g, void* l) {
  __builtin_amdgcn_global_load_lds(
      (const __attribute__((address_space(1))) void*)g,
      (__attribute__((address_space(3))) void*)l,
      16, 0, 0);
}

// ---------------- Kernel 0: hid fp32->bf16 + W conv + segment boundaries -----
// hid conversion (128 MiB read, 64 MiB write, streaming) serves two purposes:
// (a) the segmean gather then moves HALF the bytes with HALF the cache-line
// requests per wave (ushort4 vs float4), and (b) hidb is L3-resident (dirty)
// when the gather runs -- the harness's 512 MiB ws re-poison flushes L3 every
// iteration, so the fp32 gather was running at cold-HBM latency (~900 cy/line,
// measured ~2.9 TB/s request rate). Warm L3 + half the lines => ~3x gather.
__global__ void prep_kernel(const float* __restrict__ hid, unsigned short* __restrict__ hidb,
                            const float* __restrict__ W, unsigned short* __restrict__ Wb,
                            const int* __restrict__ seg, int* __restrict__ starts) {
  const int b = blockIdx.x;
  if (b < 32768) {                     // hid: 32M floats, 1024 per block
    int i = (b * 256 + threadIdx.x) * 4;
    float4 v = *(const float4*)(hid + (size_t)i);
    ushort4 o;
    o.x = f2bf(v.x); o.y = f2bf(v.y); o.z = f2bf(v.z); o.w = f2bf(v.w);
    *(ushort4*)(hidb + (size_t)i) = o;
  } else if (b < 32768 + 1024) {       // W: 1M floats
    int i = ((b - 32768) * 256 + threadIdx.x) * 4;
    float4 v = *(const float4*)(W + i);
    ushort4 o;
    o.x = f2bf(v.x); o.y = f2bf(v.y); o.z = f2bf(v.z); o.w = f2bf(v.w);
    *(ushort4*)(Wb + i) = o;
  } else {                             // segment boundaries
    int i = (b - 32768 - 1024) * 256 + threadIdx.x;
    if (i > NIDX) return;
    int prev = (i == 0) ? -1 : seg[i - 1];
    int cur  = (i == NIDX) ? NSEG : seg[i];
    for (int g = prev + 1; g <= cur; ++g) starts[g] = i;
  }
}

// ---------------- Kernel 1: segment mean (bf16 gather, fp32 accum) -----------
// Index quads are hand-prefetched one group ahead so the idx->row dependency
// chain overlaps the previous group's row loads.
__global__ void segmean_kernel(const unsigned short* __restrict__ hidb,
                               const int* __restrict__ indices,
                               const int* __restrict__ starts,
                               unsigned short* __restrict__ hb,
                               float* __restrict__ out,
                               const float* __restrict__ b_proj) {
  const int g = blockIdx.x;
  const int t = threadIdx.x;
  const int start = starts[g];
  const int end   = starts[g + 1];
  const int col   = t * 4;

  float4 a0 = make_float4(0.f, 0.f, 0.f, 0.f);
  float4 a1 = a0, a2 = a0, a3 = a0;

  int i = start;
  int j0 = 0, j1 = 0, j2 = 0, j3 = 0;
  bool have = (i + 4 <= end);
  if (have) { j0 = indices[i]; j1 = indices[i + 1]; j2 = indices[i + 2]; j3 = indices[i + 3]; }
  while (have) {
    const int r0 = j0, r1 = j1, r2 = j2, r3 = j3;
    i += 4;
    have = (i + 4 <= end);
    if (have) { j0 = indices[i]; j1 = indices[i + 1]; j2 = indices[i + 2]; j3 = indices[i + 3]; }
    ushort4 u0 = *(const ushort4*)(hidb + (size_t)r0 * HDIM + col);
    ushort4 u1 = *(const ushort4*)(hidb + (size_t)r1 * HDIM + col);
    ushort4 u2 = *(const ushort4*)(hidb + (size_t)r2 * HDIM + col);
    ushort4 u3 = *(const ushort4*)(hidb + (size_t)r3 * HDIM + col);
    a0.x += bf2f(u0.x); a0.y += bf2f(u0.y); a0.z += bf2f(u0.z); a0.w += bf2f(u0.w);
    a1.x += bf2f(u1.x); a1.y += bf2f(u1.y); a1.z += bf2f(u1.z); a1.w += bf2f(u1.w);
    a2.x += bf2f(u2.x); a2.y += bf2f(u2.y); a2.z += bf2f(u2.z); a2.w += bf2f(u2.w);
    a3.x += bf2f(u3.x); a3.y += bf2f(u3.y); a3.z += bf2f(u3.z); a3.w += bf2f(u3.w);
  }
  for (; i < end; ++i) {
    const int r = indices[i];
    ushort4 u = *(const ushort4*)(hidb + (size_t)r * HDIM + col);
    a0.x += bf2f(u.x); a0.y += bf2f(u.y); a0.z += bf2f(u.z); a0.w += bf2f(u.w);
  }
  a0.x += a1.x + a2.x + a3.x;
  a0.y += a1.y + a2.y + a3.y;
  a0.z += a1.z + a2.z + a3.z;
  a0.w += a1.w + a2.w + a3.w;

  const float inv = 1.0f / fmaxf((float)(end - start), 1.0f);
  ushort4 o;
  o.x = f2bf(a0.x * inv); o.y = f2bf(a0.y * inv);
  o.z = f2bf(a0.z * inv); o.w = f2bf(a0.w * inv);
  *(ushort4*)(hb + (size_t)g * HDIM + col) = o;

  if (t == 0) out[g] = b_proj[0];
}

// ---------------- Kernel 2: fused GEMM + bias + erf-GELU + proj ----------------
// (Best-measured R2 version: C tile 128x128, BK=128, 512 threads = 8 waves
// (2m x 4n), wave tile 64x32; global_load_lds staging with XOR slot swizzle.)
// Grid (x = m-tile 64, y = n-tile 8): linear id = y*64+x -> XCD = x%8, so all 8
// n-blocks of an m-tile co-reside on one XCD; per-XCD L2 working set ~4 MiB.
__global__ void __launch_bounds__(512)
gemm_gelu_proj_kernel(const unsigned short* __restrict__ A,   // h  [NSEG,KD] bf16
                      const unsigned short* __restrict__ Bw,  // W  [ND,KD]  bf16
                      const float* __restrict__ b_dense,
                      const float* __restrict__ w_proj,
                      float* __restrict__ out) {
  __shared__ alignas(16) unsigned short As[128 * 128];  // 32 KiB
  __shared__ alignas(16) unsigned short Bs[128 * 128];  // 32 KiB

  const int tid  = threadIdx.x;
  const int lane = tid & 63;
  const int wave = tid >> 6;       // 0..7
  const int wm   = wave >> 2;      // 0..1 -> 64 rows
  const int wn   = wave & 3;       // 0..3 -> 32 cols
  const int m0   = blockIdx.x * 128;
  const int n0   = blockIdx.y * 128;
  const int lr   = lane & 15;
  const int quad = lane >> 4;

  f32x4 acc[4][2];
#pragma unroll
  for (int mi = 0; mi < 4; ++mi)
#pragma unroll
    for (int ni = 0; ni < 2; ++ni) {
      acc[mi][ni][0] = 0.f; acc[mi][ni][1] = 0.f;
      acc[mi][ni][2] = 0.f; acc[mi][ni][3] = 0.f;
    }

  for (int kt = 0; kt < KD / 128; ++kt) {
    const int k0 = kt * 128;
#pragma unroll
    for (int j = 0; j < 4; ++j) {
      int c   = j * 512 + wave * 64 + lane;
      int row = c >> 4, sl = c & 15;
      int kcg = sl ^ (row & 15);
      async16(A + (size_t)(m0 + row) * KD + k0 + kcg * 8,
              (char*)As + (j * 512 + wave * 64) * 16);
    }
#pragma unroll
    for (int j = 0; j < 4; ++j) {
      int c   = j * 512 + wave * 64 + lane;
      int row = c >> 4, sl = c & 15;
      int kcg = sl ^ (row & 15);
      async16(Bw + (size_t)(n0 + row) * KD + k0 + kcg * 8,
              (char*)Bs + (j * 512 + wave * 64) * 16);
    }
    __syncthreads();

#pragma unroll
    for (int s = 0; s < 4; ++s) {           // four k-steps of 32
      bf16x8 af[4], bf_[2];
#pragma unroll
      for (int i = 0; i < 4; ++i) {
        int ra   = wm * 64 + i * 16 + lr;
        int slot = (s * 4 + quad) ^ (ra & 15);
        af[i] = *(const bf16x8*)(As + ra * 128 + slot * 8);
      }
#pragma unroll
      for (int i = 0; i < 2; ++i) {
        int rb   = wn * 32 + i * 16 + lr;
        int slot = (s * 4 + quad) ^ (rb & 15);
        bf_[i] = *(const bf16x8*)(Bs + rb * 128 + slot * 8);
      }
#pragma unroll
      for (int mi = 0; mi < 4; ++mi)
#pragma unroll
        for (int ni = 0; ni < 2; ++ni)
          acc[mi][ni] = __builtin_amdgcn_mfma_f32_16x16x32_bf16(af[mi], bf_[ni], acc[mi][ni], 0, 0, 0);
    }
    __syncthreads();
  }

#pragma unroll
  for (int mi = 0; mi < 4; ++mi) {
    float rp[4] = {0.f, 0.f, 0.f, 0.f};
#pragma unroll
    for (int ni = 0; ni < 2; ++ni) {
      int col  = n0 + wn * 32 + ni * 16 + lr;
      float bd = b_dense[col];
      float wp = w_proj[col];
#pragma unroll
      for (int r = 0; r < 4; ++r) {
        float v  = acc[mi][ni][r] + bd;
        float gl = 0.5f * v * (1.0f + erff(v * 0.70710678118654752f));
        rp[r] += gl * wp;
      }
    }
#pragma unroll
    for (int r = 0; r < 4; ++r) {
      float c = rp[r];
      c += __shfl_xor(c, 1);
      c += __shfl_xor(c, 2);
      c += __shfl_xor(c, 4);
      c += __shfl_xor(c, 8);
      if (lr == 0)
        atomicAdd(out + (m0 + wm * 64 + mi * 16 + quad * 4 + r), c);
    }
  }
}

extern "C" void kernel_launch(void* const* d_in, const int* in_sizes, int n_in,
                              void* d_out, int out_size, void* d_ws, size_t ws_size,
                              hipStream_t stream) {
  const float* hid     = (const float*)d_in[0];
  const int*   indices = (const int*)d_in[1];
  const int*   seg     = (const int*)d_in[2];
  const float* W_dense = (const float*)d_in[3];
  const float* b_dense = (const float*)d_in[4];
  const float* W_proj  = (const float*)d_in[5];
  const float* b_proj  = (const float*)d_in[6];
  float* out = (float*)d_out;

  // ws: hb [NSEG*KD]bf16 16MiB | Wb [ND*KD]bf16 2MiB | starts[NSEG+1] | hidb [BH*HDIM]bf16 64MiB
  unsigned short* hb     = (unsigned short*)d_ws;
  unsigned short* Wb     = (unsigned short*)((char*)d_ws + (size_t)NSEG * KD * 2);
  int*            starts = (int*)((char*)d_ws + (size_t)NSEG * KD * 2 + (size_t)ND * KD * 2);
  size_t off = (size_t)NSEG * KD * 2 + (size_t)ND * KD * 2 + (size_t)(NSEG + 1) * 4;
  off = (off + 255) & ~(size_t)255;
  unsigned short* hidb = (unsigned short*)((char*)d_ws + off);

  prep_kernel<<<dim3(32768 + 1024 + (NIDX + 256) / 256), 256, 0, stream>>>(
      hid, hidb, W_dense, Wb, seg, starts);
  segmean_kernel<<<dim3(NSEG), 256, 0, stream>>>(hidb, indices, starts, hb, out, b_proj);
  gemm_gelu_proj_kernel<<<dim3(NSEG / 128, ND / 128), 512, 0, stream>>>(hb, Wb, b_dense, W_proj, out);
}

// Round 6
// 235.614 us; speedup vs baseline: 1.0657x; 1.0657x over previous
//
#include <hip/hip_runtime.h>
#include <stdint.h>

#define BH   (8 * 4096)
#define HDIM 1024
#define NIDX 65536
#define NSEG 8192
#define KD   1024
#define ND   1024

typedef __bf16 bf16x8 __attribute__((ext_vector_type(8)));
typedef float  f32x4  __attribute__((ext_vector_type(4)));

__device__ __forceinline__ unsigned short f2bf(float f) {
  unsigned int u = __float_as_uint(f);
  u += 0x7fffu + ((u >> 16) & 1u);   // RNE
  return (unsigned short)(u >> 16);
}

__device__ __forceinline__ void async16(const void* g, void* l) {
  __builtin_amdgcn_global_load_lds(
      (const __attribute__((address_space(1))) void*)g,
      (__attribute__((address_space(3))) void*)l,
      16, 0, 0);
}

// ---------------- Kernel 0: fused W conv (bf16) + segment boundaries ----------------
__global__ void prep_kernel(const float* __restrict__ W, unsigned short* __restrict__ Wb,
                            const int* __restrict__ seg, int* __restrict__ starts) {
  if (blockIdx.x < 1024) {
    int i = (blockIdx.x * 256 + threadIdx.x) * 4;
    float4 v = *(const float4*)(W + i);
    ushort4 o;
    o.x = f2bf(v.x); o.y = f2bf(v.y); o.z = f2bf(v.z); o.w = f2bf(v.w);
    *(ushort4*)(Wb + i) = o;
  } else {
    int i = (blockIdx.x - 1024) * 256 + threadIdx.x;
    if (i > NIDX) return;
    int prev = (i == 0) ? -1 : seg[i - 1];
    int cur  = (i == NIDX) ? NSEG : seg[i];
    for (int g = prev + 1; g <= cur; ++g) starts[g] = i;
  }
}

// ---------------- Kernel 1: segment mean -> h (bf16), init out ----------------
// Latency-bound gather (R5 falsified byte-bound theory): keep 8 rows in flight
// per block (vs 4) and prefetch the next index group before waiting on the
// current row group. Accumulation order is BIT-IDENTICAL to the R2 kernel:
// a0 gets rows 0,4,8,...; tail rows append to a0 in sequence.
__global__ void segmean_kernel(const float* __restrict__ hid,
                               const int* __restrict__ indices,
                               const int* __restrict__ starts,
                               unsigned short* __restrict__ hb,
                               float* __restrict__ out,
                               const float* __restrict__ b_proj) {
  const int g = blockIdx.x;
  const int t = threadIdx.x;
  const int start = starts[g];
  const int end   = starts[g + 1];
  const int col   = t * 4;

  float4 a0 = make_float4(0.f, 0.f, 0.f, 0.f);
  float4 a1 = a0, a2 = a0, a3 = a0;

  int i = start;
  int r0 = 0, r1 = 0, r2 = 0, r3 = 0, r4 = 0, r5 = 0, r6 = 0, r7 = 0;
  bool have = (i + 8 <= end);
  if (have) {
    r0 = indices[i];     r1 = indices[i + 1]; r2 = indices[i + 2]; r3 = indices[i + 3];
    r4 = indices[i + 4]; r5 = indices[i + 5]; r6 = indices[i + 6]; r7 = indices[i + 7];
  }
  while (have) {
    // 8 independent row loads in flight
    float4 v0 = *(const float4*)(hid + (size_t)r0 * HDIM + col);
    float4 v1 = *(const float4*)(hid + (size_t)r1 * HDIM + col);
    float4 v2 = *(const float4*)(hid + (size_t)r2 * HDIM + col);
    float4 v3 = *(const float4*)(hid + (size_t)r3 * HDIM + col);
    float4 v4 = *(const float4*)(hid + (size_t)r4 * HDIM + col);
    float4 v5 = *(const float4*)(hid + (size_t)r5 * HDIM + col);
    float4 v6 = *(const float4*)(hid + (size_t)r6 * HDIM + col);
    float4 v7 = *(const float4*)(hid + (size_t)r7 * HDIM + col);
    i += 8;
    have = (i + 8 <= end);
    if (have) {
      r0 = indices[i];     r1 = indices[i + 1]; r2 = indices[i + 2]; r3 = indices[i + 3];
      r4 = indices[i + 4]; r5 = indices[i + 5]; r6 = indices[i + 6]; r7 = indices[i + 7];
    }
    a0.x += v0.x; a0.y += v0.y; a0.z += v0.z; a0.w += v0.w;
    a1.x += v1.x; a1.y += v1.y; a1.z += v1.z; a1.w += v1.w;
    a2.x += v2.x; a2.y += v2.y; a2.z += v2.z; a2.w += v2.w;
    a3.x += v3.x; a3.y += v3.y; a3.z += v3.z; a3.w += v3.w;
    a0.x += v4.x; a0.y += v4.y; a0.z += v4.z; a0.w += v4.w;
    a1.x += v5.x; a1.y += v5.y; a1.z += v5.z; a1.w += v5.w;
    a2.x += v6.x; a2.y += v6.y; a2.z += v6.z; a2.w += v6.w;
    a3.x += v7.x; a3.y += v7.y; a3.z += v7.z; a3.w += v7.w;
  }
  if (i + 4 <= end) {
    int s0 = indices[i], s1 = indices[i + 1], s2 = indices[i + 2], s3 = indices[i + 3];
    float4 v0 = *(const float4*)(hid + (size_t)s0 * HDIM + col);
    float4 v1 = *(const float4*)(hid + (size_t)s1 * HDIM + col);
    float4 v2 = *(const float4*)(hid + (size_t)s2 * HDIM + col);
    float4 v3 = *(const float4*)(hid + (size_t)s3 * HDIM + col);
    a0.x += v0.x; a0.y += v0.y; a0.z += v0.z; a0.w += v0.w;
    a1.x += v1.x; a1.y += v1.y; a1.z += v1.z; a1.w += v1.w;
    a2.x += v2.x; a2.y += v2.y; a2.z += v2.z; a2.w += v2.w;
    a3.x += v3.x; a3.y += v3.y; a3.z += v3.z; a3.w += v3.w;
    i += 4;
  }
  {
    // tail (<=3 rows): loads issued together, adds applied in order to a0
    const int rem = end - i;
    if (rem > 0) {
      int s0 = indices[i];
      float4 w0 = *(const float4*)(hid + (size_t)s0 * HDIM + col);
      float4 w1, w2;
      if (rem > 1) { int s1 = indices[i + 1]; w1 = *(const float4*)(hid + (size_t)s1 * HDIM + col); }
      if (rem > 2) { int s2 = indices[i + 2]; w2 = *(const float4*)(hid + (size_t)s2 * HDIM + col); }
      a0.x += w0.x; a0.y += w0.y; a0.z += w0.z; a0.w += w0.w;
      if (rem > 1) { a0.x += w1.x; a0.y += w1.y; a0.z += w1.z; a0.w += w1.w; }
      if (rem > 2) { a0.x += w2.x; a0.y += w2.y; a0.z += w2.z; a0.w += w2.w; }
    }
  }
  a0.x += a1.x + a2.x + a3.x;
  a0.y += a1.y + a2.y + a3.y;
  a0.z += a1.z + a2.z + a3.z;
  a0.w += a1.w + a2.w + a3.w;

  const float inv = 1.0f / fmaxf((float)(end - start), 1.0f);
  ushort4 o;
  o.x = f2bf(a0.x * inv); o.y = f2bf(a0.y * inv);
  o.z = f2bf(a0.z * inv); o.w = f2bf(a0.w * inv);
  *(ushort4*)(hb + (size_t)g * HDIM + col) = o;

  if (t == 0) out[g] = b_proj[0];
}

// ---------------- Kernel 2: fused GEMM + bias + erf-GELU + proj ----------------
// (Best-measured R2 version: C tile 128x128, BK=128, 512 threads = 8 waves
// (2m x 4n), wave tile 64x32; global_load_lds staging with XOR slot swizzle.)
// Grid (x = m-tile 64, y = n-tile 8): linear id = y*64+x -> XCD = x%8, so all 8
// n-blocks of an m-tile co-reside on one XCD; per-XCD L2 working set ~4 MiB.
__global__ void __launch_bounds__(512)
gemm_gelu_proj_kernel(const unsigned short* __restrict__ A,   // h  [NSEG,KD] bf16
                      const unsigned short* __restrict__ Bw,  // W  [ND,KD]  bf16
                      const float* __restrict__ b_dense,
                      const float* __restrict__ w_proj,
                      float* __restrict__ out) {
  __shared__ alignas(16) unsigned short As[128 * 128];  // 32 KiB
  __shared__ alignas(16) unsigned short Bs[128 * 128];  // 32 KiB

  const int tid  = threadIdx.x;
  const int lane = tid & 63;
  const int wave = tid >> 6;       // 0..7
  const int wm   = wave >> 2;      // 0..1 -> 64 rows
  const int wn   = wave & 3;       // 0..3 -> 32 cols
  const int m0   = blockIdx.x * 128;
  const int n0   = blockIdx.y * 128;
  const int lr   = lane & 15;
  const int quad = lane >> 4;

  f32x4 acc[4][2];
#pragma unroll
  for (int mi = 0; mi < 4; ++mi)
#pragma unroll
    for (int ni = 0; ni < 2; ++ni) {
      acc[mi][ni][0] = 0.f; acc[mi][ni][1] = 0.f;
      acc[mi][ni][2] = 0.f; acc[mi][ni][3] = 0.f;
    }

  for (int kt = 0; kt < KD / 128; ++kt) {
    const int k0 = kt * 128;
#pragma unroll
    for (int j = 0; j < 4; ++j) {
      int c   = j * 512 + wave * 64 + lane;
      int row = c >> 4, sl = c & 15;
      int kcg = sl ^ (row & 15);
      async16(A + (size_t)(m0 + row) * KD + k0 + kcg * 8,
              (char*)As + (j * 512 + wave * 64) * 16);
    }
#pragma unroll
    for (int j = 0; j < 4; ++j) {
      int c   = j * 512 + wave * 64 + lane;
      int row = c >> 4, sl = c & 15;
      int kcg = sl ^ (row & 15);
      async16(Bw + (size_t)(n0 + row) * KD + k0 + kcg * 8,
              (char*)Bs + (j * 512 + wave * 64) * 16);
    }
    __syncthreads();

#pragma unroll
    for (int s = 0; s < 4; ++s) {           // four k-steps of 32
      bf16x8 af[4], bf_[2];
#pragma unroll
      for (int i = 0; i < 4; ++i) {
        int ra   = wm * 64 + i * 16 + lr;
        int slot = (s * 4 + quad) ^ (ra & 15);
        af[i] = *(const bf16x8*)(As + ra * 128 + slot * 8);
      }
#pragma unroll
      for (int i = 0; i < 2; ++i) {
        int rb   = wn * 32 + i * 16 + lr;
        int slot = (s * 4 + quad) ^ (rb & 15);
        bf_[i] = *(const bf16x8*)(Bs + rb * 128 + slot * 8);
      }
#pragma unroll
      for (int mi = 0; mi < 4; ++mi)
#pragma unroll
        for (int ni = 0; ni < 2; ++ni)
          acc[mi][ni] = __builtin_amdgcn_mfma_f32_16x16x32_bf16(af[mi], bf_[ni], acc[mi][ni], 0, 0, 0);
    }
    __syncthreads();
  }

#pragma unroll
  for (int mi = 0; mi < 4; ++mi) {
    float rp[4] = {0.f, 0.f, 0.f, 0.f};
#pragma unroll
    for (int ni = 0; ni < 2; ++ni) {
      int col  = n0 + wn * 32 + ni * 16 + lr;
      float bd = b_dense[col];
      float wp = w_proj[col];
#pragma unroll
      for (int r = 0; r < 4; ++r) {
        float v  = acc[mi][ni][r] + bd;
        float gl = 0.5f * v * (1.0f + erff(v * 0.70710678118654752f));
        rp[r] += gl * wp;
      }
    }
#pragma unroll
    for (int r = 0; r < 4; ++r) {
      float c = rp[r];
      c += __shfl_xor(c, 1);
      c += __shfl_xor(c, 2);
      c += __shfl_xor(c, 4);
      c += __shfl_xor(c, 8);
      if (lr == 0)
        atomicAdd(out + (m0 + wm * 64 + mi * 16 + quad * 4 + r), c);
    }
  }
}

extern "C" void kernel_launch(void* const* d_in, const int* in_sizes, int n_in,
                              void* d_out, int out_size, void* d_ws, size_t ws_size,
                              hipStream_t stream) {
  const float* hid     = (const float*)d_in[0];
  const int*   indices = (const int*)d_in[1];
  const int*   seg     = (const int*)d_in[2];
  const float* W_dense = (const float*)d_in[3];
  const float* b_dense = (const float*)d_in[4];
  const float* W_proj  = (const float*)d_in[5];
  const float* b_proj  = (const float*)d_in[6];
  float* out = (float*)d_out;

  // ws layout: h_bf16 [NSEG*KD] (16 MiB) | W_bf16 [ND*KD] (2 MiB) | starts [NSEG+1]
  unsigned short* hb     = (unsigned short*)d_ws;
  unsigned short* Wb     = (unsigned short*)((char*)d_ws + (size_t)NSEG * KD * 2);
  int*            starts = (int*)((char*)d_ws + (size_t)NSEG * KD * 2 + (size_t)ND * KD * 2);

  prep_kernel<<<dim3(1024 + (NIDX + 256) / 256), 256, 0, stream>>>(W_dense, Wb, seg, starts);
  segmean_kernel<<<dim3(NSEG), 256, 0, stream>>>(hid, indices, starts, hb, out, b_proj);
  gemm_gelu_proj_kernel<<<dim3(NSEG / 128, ND / 128), 512, 0, stream>>>(hb, Wb, b_dense, W_proj, out);
}